// Round 2
// baseline (21824.445 us; speedup 1.0000x reference)
//
#include <hip/hip_runtime.h>
#include <math.h>

#define NPATH   16      // paths per block
#define NGRP    16      // neuron-groups per path
#define TPB     256
#define NBLOCKS 512     // 8192 / 16
#define BATCHN  8192
#define NMAT    4
#define PERS    24
#define NK      201
#define ASTR    100     // padded activation row stride (floats), %4==0, %32!=0

__device__ __forceinline__ float frelu(float x){ return x > 0.f ? x : 0.f; }
__device__ __forceinline__ float dot4(const float4 a, const float4 b){
  return a.x*b.x + a.y*b.y + a.z*b.z + a.w*b.w;
}

__global__ __launch_bounds__(TPB, 2)
void sde_kernel(const float* __restrict__ nW0, const float* __restrict__ nb0,
                const float* __restrict__ nW1, const float* __restrict__ nb1,
                const float* __restrict__ nW2, const float* __restrict__ nb2,
                const float* __restrict__ nW3, const float* __restrict__ nb3,
                const float* __restrict__ hW0, const float* __restrict__ hb0,
                const float* __restrict__ hW1, const float* __restrict__ hb1,
                const float* __restrict__ hW2, const float* __restrict__ hb2,
                const float* __restrict__ hW3, const float* __restrict__ hb3,
                const float* __restrict__ hW4, const float* __restrict__ hb4,
                const float* __restrict__ rho, const float* __restrict__ V0,
                const float* __restrict__ strikes,
                const float* __restrict__ noise1, const float* __restrict__ noise2,
                double* __restrict__ accS, double* __restrict__ accS2)
{
  __shared__ float bufA[NPATH][ASTR];
  __shared__ float bufB[NPATH][ASTR];
  __shared__ float Gst[NPATH][NMAT*64];   // per-path, per-period G vectors (persist across periods)
  __shared__ float Sarr[NPATH], Varr[NPATH], carr[NPATH];
  __shared__ float rawL[3][NPATH];
  __shared__ float Cst[NMAT][NPATH];

  const int tid   = threadIdx.x;
  const int p     = tid & (NPATH-1);
  const int g     = tid >> 4;
  const int gpath = blockIdx.x * NPATH + p;

  const float  DTf  = (float)(2.0/96.0);
  const float  SDT  = (float)0.14433756729740643;   // sqrt(2/96)
  const float  DFf  = (float)exp(-0.05 * (2.0/96.0));
  const float  rho_s = rho[0];
  const float  rt1m  = sqrtf(fmaxf(0.f, 1.f - rho_s*rho_s));

  if (g == 0){ Sarr[p] = 100.f; Varr[p] = V0[0]; }

#pragma unroll
  for (int m = 0; m < NMAT; ++m){
    float Greg0 = 0.f, Greg1 = 0.f, Greg2 = 0.f, Greg3 = 0.f;
    float Cacc  = 0.f;

#pragma unroll 1
    for (int s = 0; s < PERS; ++s){
      const int   gstep = m*PERS + s;
      const float t     = (float)gstep * DTf;

      __syncthreads();   // protects bufA reuse + Sarr/Varr init/update visibility

      // ---------- drift L0: 96 rows (3 nets x 32), input [t, S, V] -> bufA
      {
        const float S = Sarr[p], V = Varr[p];
#pragma unroll
        for (int j = 0; j < 6; ++j){
          const int r = g*6 + j, n = r >> 5, o = r & 31;
          const float* w = nW0 + (size_t)((n*4+m)*32 + o) * 3;
          bufA[p][r] = frelu(w[0]*t + w[1]*S + w[2]*V + nb0[(n*4+m)*32 + o]);
        }
      }
      __syncthreads();

      // ---------- drift L1: bufA -> bufB
#pragma unroll
      for (int j = 0; j < 6; ++j){
        const int r = g*6 + j, n = r >> 5, o = r & 31;
        const float* w   = nW1 + (size_t)((n*4+m)*32 + o) * 32;
        const float* hin = &bufA[p][n*32];
        float acc = nb1[(n*4+m)*32 + o];
#pragma unroll
        for (int k = 0; k < 32; k += 4)
          acc += dot4(*(const float4*)(w + k), *(const float4*)(hin + k));
        bufB[p][r] = frelu(acc);
      }
      __syncthreads();

      // ---------- drift L2: bufB -> bufA
#pragma unroll
      for (int j = 0; j < 6; ++j){
        const int r = g*6 + j, n = r >> 5, o = r & 31;
        const float* w   = nW2 + (size_t)((n*4+m)*32 + o) * 32;
        const float* hin = &bufB[p][n*32];
        float acc = nb2[(n*4+m)*32 + o];
#pragma unroll
        for (int k = 0; k < 32; k += 4)
          acc += dot4(*(const float4*)(w + k), *(const float4*)(hin + k));
        bufA[p][r] = frelu(acc);
      }
      __syncthreads();

      // ---------- drift L3 (3 outputs, g<3) + hedge L0 (64 rows, all threads)
      if (g < 3){
        const float* w   = nW3 + (size_t)(g*4 + m) * 32;
        const float* hin = &bufA[p][g*32];
        float acc = nb3[g*4 + m];
#pragma unroll
        for (int k = 0; k < 32; k += 4)
          acc += dot4(*(const float4*)(w + k), *(const float4*)(hin + k));
        rawL[g][p] = acc;
      }
      {
        const float S = Sarr[p];   // pre-update S (stop_gradient(S))
        float h0, h1, h2, h3;
        {
          const int o = g*4;
          const float* w = hW0 + (size_t)(m*64 + o) * 2;
          h0 = frelu(w[0]*t + w[1]*S + hb0[m*64 + o + 0]);
          h1 = frelu(w[2]*t + w[3]*S + hb0[m*64 + o + 1]);
          h2 = frelu(w[4]*t + w[5]*S + hb0[m*64 + o + 2]);
          h3 = frelu(w[6]*t + w[7]*S + hb0[m*64 + o + 3]);
        }
        *(float4*)&bufB[p][g*4] = make_float4(h0, h1, h2, h3);
      }
      __syncthreads();

      // ---------- per-path scalar SDE update (one thread per path)
      if (g == 0){
        const float r0 = rawL[0][p], r1 = rawL[1][p], r2 = rawL[2][p];
        const float sigS = r0 / (1.f + fabsf(r0)*SDT);
        const float bV   = r1 / (1.f + fabsf(r1)*SDT);
        const float sigV = r2 / (1.f + fabsf(r2)*SDT);
        const float S = Sarr[p], V = Varr[p];
        const float sr = S * 0.05f;
        const float bS = sr / (1.f + fabsf(sr)*SDT);
        const float n1 = noise1[(size_t)gstep*BATCHN + gpath];
        const float n2 = noise2[(size_t)gstep*BATCHN + gpath];
        const float dWv = SDT * n2;
        const float dB  = rho_s*dWv + rt1m*SDT*n1;
        const float c   = DFf * S * sigS * dWv;
        carr[p] = c;
        Cacc   += c;
        Sarr[p] = S + bS*DTf + sigS*dB;
        Varr[p] = frelu(V + bV*DTf + sigV*dWv);
      }
      __syncthreads();

      // ---------- hedge L1: bufB -> bufA (4 rows/thread, share h4 loads)
      {
        const int o0 = g*4;
        const float* w0 = hW1 + (size_t)(m*64 + o0    )*64;
        const float* w1 = hW1 + (size_t)(m*64 + o0 + 1)*64;
        const float* w2 = hW1 + (size_t)(m*64 + o0 + 2)*64;
        const float* w3 = hW1 + (size_t)(m*64 + o0 + 3)*64;
        float a0 = hb1[m*64+o0], a1 = hb1[m*64+o0+1], a2 = hb1[m*64+o0+2], a3 = hb1[m*64+o0+3];
#pragma unroll
        for (int k = 0; k < 64; k += 4){
          const float4 h4 = *(const float4*)&bufB[p][k];
          a0 += dot4(*(const float4*)(w0 + k), h4);
          a1 += dot4(*(const float4*)(w1 + k), h4);
          a2 += dot4(*(const float4*)(w2 + k), h4);
          a3 += dot4(*(const float4*)(w3 + k), h4);
        }
        *(float4*)&bufA[p][o0] = make_float4(frelu(a0), frelu(a1), frelu(a2), frelu(a3));
      }
      __syncthreads();

      // ---------- hedge L2: bufA -> bufB
      {
        const int o0 = g*4;
        const float* w0 = hW2 + (size_t)(m*64 + o0    )*64;
        const float* w1 = hW2 + (size_t)(m*64 + o0 + 1)*64;
        const float* w2 = hW2 + (size_t)(m*64 + o0 + 2)*64;
        const float* w3 = hW2 + (size_t)(m*64 + o0 + 3)*64;
        float a0 = hb2[m*64+o0], a1 = hb2[m*64+o0+1], a2 = hb2[m*64+o0+2], a3 = hb2[m*64+o0+3];
#pragma unroll
        for (int k = 0; k < 64; k += 4){
          const float4 h4 = *(const float4*)&bufA[p][k];
          a0 += dot4(*(const float4*)(w0 + k), h4);
          a1 += dot4(*(const float4*)(w1 + k), h4);
          a2 += dot4(*(const float4*)(w2 + k), h4);
          a3 += dot4(*(const float4*)(w3 + k), h4);
        }
        *(float4*)&bufB[p][o0] = make_float4(frelu(a0), frelu(a1), frelu(a2), frelu(a3));
      }
      __syncthreads();

      // ---------- hedge L3: bufB -> bufA
      {
        const int o0 = g*4;
        const float* w0 = hW3 + (size_t)(m*64 + o0    )*64;
        const float* w1 = hW3 + (size_t)(m*64 + o0 + 1)*64;
        const float* w2 = hW3 + (size_t)(m*64 + o0 + 2)*64;
        const float* w3 = hW3 + (size_t)(m*64 + o0 + 3)*64;
        float a0 = hb3[m*64+o0], a1 = hb3[m*64+o0+1], a2 = hb3[m*64+o0+2], a3 = hb3[m*64+o0+3];
#pragma unroll
        for (int k = 0; k < 64; k += 4){
          const float4 h4 = *(const float4*)&bufB[p][k];
          a0 += dot4(*(const float4*)(w0 + k), h4);
          a1 += dot4(*(const float4*)(w1 + k), h4);
          a2 += dot4(*(const float4*)(w2 + k), h4);
          a3 += dot4(*(const float4*)(w3 + k), h4);
        }
        *(float4*)&bufA[p][o0] = make_float4(frelu(a0), frelu(a1), frelu(a2), frelu(a3));
      }
      __syncthreads();

      // ---------- accumulate G += c * h3   (4 neurons/thread, registers)
      {
        const float c  = carr[p];
        const float4 hv = *(const float4*)&bufA[p][g*4];
        Greg0 += c * hv.x;
        Greg1 += c * hv.y;
        Greg2 += c * hv.z;
        Greg3 += c * hv.w;
      }
    } // steps

    // ---------- period end: stash G/C, compute payoff for maturity m
    Gst[p][m*64 + g*4 + 0] = Greg0;
    Gst[p][m*64 + g*4 + 1] = Greg1;
    Gst[p][m*64 + g*4 + 2] = Greg2;
    Gst[p][m*64 + g*4 + 3] = Greg3;
    if (g == 0) Cst[m][p] = Cacc;
    __syncthreads();

    {
      const float discm = (float)exp(-0.05 * (2.0/96.0) * (double)(PERS*(m+1)));
      const float Sfin  = Sarr[p];
      for (int k = g; k < NK; k += NGRP){
        const int r = k*4 + m;
        float acc = 0.f;
        for (int q = 0; q <= m; ++q){
          const float* w  = hW4 + (size_t)(q*804 + r) * 64;
          const float* gv = &Gst[p][q*64];
          float a = hb4[q*804 + r] * Cst[q][p];
#pragma unroll
          for (int kk = 0; kk < 64; kk += 4)
            a += dot4(*(const float4*)(w + kk), *(const float4*)(gv + kk));
          acc += a;
        }
        const float pay = discm * frelu(Sfin - strikes[k]) - acc;
        float s1 = pay, s2 = pay*pay;
        // reduce over the 16 paths of this block (contiguous 16-lane segment)
        for (int d = 8; d > 0; d >>= 1){
          s1 += __shfl_down(s1, d, 16);
          s2 += __shfl_down(s2, d, 16);
        }
        if (p == 0){
          atomicAdd(&accS [m*NK + k], (double)s1);
          atomicAdd(&accS2[m*NK + k], (double)s2);
        }
      }
    }
  } // maturities
}

__global__ void finalize_kernel(const double* __restrict__ accS,
                                const double* __restrict__ accS2,
                                float* __restrict__ out)
{
  const int i = blockIdx.x * blockDim.x + threadIdx.x;
  if (i < NK*NMAT){
    const int k = i >> 2, m = i & 3;            // out layout: [k][m]
    const double s1 = accS [m*NK + k];
    const double s2 = accS2[m*NK + k];
    const double mean = s1 / 8192.0;
    const double var  = (s2 - s1*s1/8192.0) / 8191.0;   // ddof=1
    out[i]           = (float)mean;
    out[NK*NMAT + i] = (float)var;
  }
}

extern "C" void kernel_launch(void* const* d_in, const int* in_sizes, int n_in,
                              void* d_out, int out_size, void* d_ws, size_t ws_size,
                              hipStream_t stream)
{
  (void)in_sizes; (void)n_in; (void)out_size; (void)ws_size;
  const float* nW0 = (const float*)d_in[0];
  const float* nb0 = (const float*)d_in[1];
  const float* nW1 = (const float*)d_in[2];
  const float* nb1 = (const float*)d_in[3];
  const float* nW2 = (const float*)d_in[4];
  const float* nb2 = (const float*)d_in[5];
  const float* nW3 = (const float*)d_in[6];
  const float* nb3 = (const float*)d_in[7];
  const float* hW0 = (const float*)d_in[8];
  const float* hb0 = (const float*)d_in[9];
  const float* hW1 = (const float*)d_in[10];
  const float* hb1 = (const float*)d_in[11];
  const float* hW2 = (const float*)d_in[12];
  const float* hb2 = (const float*)d_in[13];
  const float* hW3 = (const float*)d_in[14];
  const float* hb3 = (const float*)d_in[15];
  const float* hW4 = (const float*)d_in[16];
  const float* hb4 = (const float*)d_in[17];
  const float* rho = (const float*)d_in[18];
  const float* V0  = (const float*)d_in[19];
  const float* strikes = (const float*)d_in[20];
  const float* noise1  = (const float*)d_in[21];
  const float* noise2  = (const float*)d_in[22];

  double* accS  = (double*)d_ws;
  double* accS2 = accS + NK*NMAT;

  hipMemsetAsync(d_ws, 0, 2 * NK * NMAT * sizeof(double), stream);

  sde_kernel<<<NBLOCKS, TPB, 0, stream>>>(nW0, nb0, nW1, nb1, nW2, nb2, nW3, nb3,
                                          hW0, hb0, hW1, hb1, hW2, hb2, hW3, hb3,
                                          hW4, hb4, rho, V0, strikes, noise1, noise2,
                                          accS, accS2);

  finalize_kernel<<<(NK*NMAT + 255)/256, 256, 0, stream>>>(accS, accS2, (float*)d_out);
}

// Round 3
// 1312.386 us; speedup vs baseline: 16.6296x; 16.6296x over previous
//
#include <hip/hip_runtime.h>
#include <math.h>

#define TPB      512
#define NPATH    32       // paths per block (4 per wave, 8 waves)
#define NBLOCKS  256
#define BATCHN   8192
#define NMAT     4
#define PERS     24
#define NK       201
#define ABUF     100      // activation row stride (floats)
#define W32P     36       // padded LDS row stride, 32-wide drift weights
#define W64P     68       // padded LDS row stride, 64-wide hedge weights
#define GSTP     260      // Gst row stride

__device__ __forceinline__ float frelu(float x){ return x > 0.f ? x : 0.f; }
__device__ __forceinline__ float dot4(float4 a, float4 b){
  return a.x*b.x + a.y*b.y + a.z*b.z + a.w*b.w;
}
// Intra-wave LDS write->read fence (cross-lane exchange, no cross-wave deps).
#define LDS_FENCE() asm volatile("s_waitcnt lgkmcnt(0)" ::: "memory")

__global__ __launch_bounds__(TPB, 2)
void sde_kernel(const float* __restrict__ nW0, const float* __restrict__ nb0,
                const float* __restrict__ nW1, const float* __restrict__ nb1,
                const float* __restrict__ nW2, const float* __restrict__ nb2,
                const float* __restrict__ nW3, const float* __restrict__ nb3,
                const float* __restrict__ hW0, const float* __restrict__ hb0,
                const float* __restrict__ hW1, const float* __restrict__ hb1,
                const float* __restrict__ hW2, const float* __restrict__ hb2,
                const float* __restrict__ hW3, const float* __restrict__ hb3,
                const float* __restrict__ hW4, const float* __restrict__ hb4,
                const float* __restrict__ rho, const float* __restrict__ V0,
                const float* __restrict__ strikes,
                const float* __restrict__ noise1, const float* __restrict__ noise2,
                float* __restrict__ part1, float* __restrict__ part2)
{
  // ---- weights for current maturity (LDS-resident) ----
  __shared__ float sW0[96*4];           // [w0,w1,w2,bias] per drift-L0 row
  __shared__ float sW1[96*W32P];
  __shared__ float sB1[96];
  __shared__ float sW2[96*W32P];
  __shared__ float sB2[96];
  __shared__ float sW3[96];
  __shared__ float sB3[4];
  __shared__ float sH0[128];
  __shared__ float sHB0[64];
  __shared__ float sH1[64*W64P];
  __shared__ float sHB1[64];
  __shared__ float sH2[64*W64P];
  __shared__ float sHB2[64];
  __shared__ float sH3[64*W64P];
  __shared__ float sHB3[64];
  // ---- per-path state / activations ----
  __shared__ float bufA[NPATH*ABUF];
  __shared__ float bufB[NPATH*ABUF];
  __shared__ float Gst[NPATH*GSTP];     // G vectors for all 4 periods
  __shared__ float Sarr[NPATH], Varr[NPATH], carr[NPATH];
  __shared__ float rawL[3*NPATH];
  __shared__ float Cst[NMAT*NPATH];
  __shared__ float psum[NK*2];

  const int tid   = threadIdx.x;
  const int lane  = tid & 63;
  const int wave  = tid >> 6;
  const int p     = lane & 3;           // path within wave
  const int g     = lane >> 2;          // neuron group 0..15
  const int bp    = wave*4 + p;         // block-path 0..31
  const int gpath = blockIdx.x * NPATH + bp;

  const float DTf = (float)(2.0/96.0);
  const float SDT = 0.14433756729740643f;          // sqrt(DT)
  const float DFf = (float)exp(-0.05 * 2.0 / 96.0);
  const float rho_s = rho[0];
  const float rt1m  = sqrtf(1.f - rho_s*rho_s);

  if (g == 0){ Sarr[bp] = 100.f; Varr[bp] = V0[0]; }

#pragma unroll 1
  for (int m = 0; m < NMAT; ++m){
    __syncthreads();   // (a) previous maturity fully done (psum writeout, weights)

    // ---------------- stage maturity-m weights into LDS ----------------
    for (int i = tid; i < 96*4; i += TPB){
      const int r = i >> 2, c = i & 3, n = r >> 5, o = r & 31;
      sW0[i] = (c < 3) ? nW0[n*384 + m*96 + o*3 + c] : nb0[n*128 + m*32 + o];
    }
    for (int i = tid; i < 3072; i += TPB){
      const int n = i >> 10, rem = i & 1023, r = i >> 5, c = i & 31;
      sW1[r*W32P + c] = nW1[n*4096 + m*1024 + rem];
      sW2[r*W32P + c] = nW2[n*4096 + m*1024 + rem];
    }
    for (int i = tid; i < 96; i += TPB){
      const int n = i >> 5, o = i & 31;
      sB1[i] = nb1[n*128 + m*32 + o];
      sB2[i] = nb2[n*128 + m*32 + o];
      sW3[i] = nW3[n*128 + m*32 + o];
    }
    if (tid < 3) sB3[tid] = nb3[tid*4 + m];
    for (int i = tid; i < 128; i += TPB) sH0[i] = hW0[m*128 + i];
    for (int i = tid; i < 64; i += TPB){
      sHB0[i] = hb0[m*64+i]; sHB1[i] = hb1[m*64+i];
      sHB2[i] = hb2[m*64+i]; sHB3[i] = hb3[m*64+i];
    }
    for (int i = tid; i < 4096; i += TPB){
      const int r = i >> 6, c = i & 63;
      sH1[r*W64P + c] = hW1[m*4096 + i];
      sH2[r*W64P + c] = hW2[m*4096 + i];
      sH3[r*W64P + c] = hW3[m*4096 + i];
    }
    for (int i = tid; i < NK*2; i += TPB) psum[i] = 0.f;
    __syncthreads();   // (b) weights + psum ready

    float Greg0 = 0.f, Greg1 = 0.f, Greg2 = 0.f, Greg3 = 0.f;
    float Cacc  = 0.f;

    // ---------------- 24 steps, NO cross-wave barriers ----------------
#pragma unroll 1
    for (int s = 0; s < PERS; ++s){
      const int   gstep = m*PERS + s;
      const float t     = (float)gstep * DTf;

      float n1r = 0.f, n2r = 0.f;
      if (g == 0){   // prefetch noise early; consumed in SDE phase
        n1r = noise1[(size_t)gstep*BATCHN + gpath];
        n2r = noise2[(size_t)gstep*BATCHN + gpath];
      }

      const float S = Sarr[bp], V = Varr[bp];   // pre-update state

      // D0: drift L0 -> bufA[96 rows]
#pragma unroll
      for (int j = 0; j < 6; ++j){
        const int r = g + 16*j;
        const float4 w = *(const float4*)&sW0[r*4];
        bufA[bp*ABUF + r] = frelu(w.x*t + w.y*S + w.z*V + w.w);
      }
      LDS_FENCE();

      // D1: bufA -> bufB
#pragma unroll
      for (int j = 0; j < 6; ++j){
        const int r = g + 16*j;
        const int n = j >> 1;
        const float* w = &sW1[r*W32P];
        const float* a = &bufA[bp*ABUF + n*32];
        float acc = sB1[r];
#pragma unroll
        for (int k = 0; k < 32; k += 4)
          acc += dot4(*(const float4*)(w+k), *(const float4*)(a+k));
        bufB[bp*ABUF + r] = frelu(acc);
      }
      LDS_FENCE();

      // D2: bufB -> bufA
#pragma unroll
      for (int j = 0; j < 6; ++j){
        const int r = g + 16*j;
        const int n = j >> 1;
        const float* w = &sW2[r*W32P];
        const float* a = &bufB[bp*ABUF + n*32];
        float acc = sB2[r];
#pragma unroll
        for (int k = 0; k < 32; k += 4)
          acc += dot4(*(const float4*)(w+k), *(const float4*)(a+k));
        bufA[bp*ABUF + r] = frelu(acc);
      }
      LDS_FENCE();

      // D3: 3 scalar outputs (lanes g<3)
      if (g < 3){
        const float* w = &sW3[g*32];
        const float* a = &bufA[bp*ABUF + g*32];
        float acc = sB3[g];
#pragma unroll
        for (int k = 0; k < 32; k += 4)
          acc += dot4(*(const float4*)(w+k), *(const float4*)(a+k));
        rawL[g*NPATH + bp] = acc;
      }
      LDS_FENCE();

      // SDE update (lane g==0 per path)
      if (g == 0){
        const float r0 = rawL[0*NPATH+bp], r1 = rawL[1*NPATH+bp], r2 = rawL[2*NPATH+bp];
        const float sigS = r0/(1.f+fabsf(r0)*SDT);
        const float bV   = r1/(1.f+fabsf(r1)*SDT);
        const float sigV = r2/(1.f+fabsf(r2)*SDT);
        const float sr = S*0.05f;
        const float bS = sr/(1.f+fabsf(sr)*SDT);
        const float dW = SDT*n2r;
        const float dB = rho_s*dW + rt1m*SDT*n1r;
        const float c  = DFf*S*sigS*dW;
        carr[bp] = c;  Cacc += c;
        Sarr[bp] = S + bS*DTf + sigS*dB;
        Varr[bp] = frelu(V + bV*DTf + sigV*dW);
      }

      // H0: hedge L0 (uses pre-update S from register) -> bufB[0..63]
#pragma unroll
      for (int rr = 0; rr < 4; ++rr){
        const int o = g + 16*rr;
        bufB[bp*ABUF + o] = frelu(sH0[o*2]*t + sH0[o*2+1]*S + sHB0[o]);
      }
      LDS_FENCE();

      // H1: bufB -> bufA
      {
        float a0 = sHB1[g], a1 = sHB1[g+16], a2 = sHB1[g+32], a3 = sHB1[g+48];
        const float* w0 = &sH1[(g    )*W64P];
        const float* w1 = &sH1[(g+16)*W64P];
        const float* w2 = &sH1[(g+32)*W64P];
        const float* w3 = &sH1[(g+48)*W64P];
        const float* a  = &bufB[bp*ABUF];
#pragma unroll
        for (int k = 0; k < 64; k += 4){
          const float4 h = *(const float4*)(a+k);
          a0 += dot4(*(const float4*)(w0+k), h);
          a1 += dot4(*(const float4*)(w1+k), h);
          a2 += dot4(*(const float4*)(w2+k), h);
          a3 += dot4(*(const float4*)(w3+k), h);
        }
        bufA[bp*ABUF + g    ] = frelu(a0);
        bufA[bp*ABUF + g+16 ] = frelu(a1);
        bufA[bp*ABUF + g+32 ] = frelu(a2);
        bufA[bp*ABUF + g+48 ] = frelu(a3);
      }
      LDS_FENCE();

      // H2: bufA -> bufB
      {
        float a0 = sHB2[g], a1 = sHB2[g+16], a2 = sHB2[g+32], a3 = sHB2[g+48];
        const float* w0 = &sH2[(g    )*W64P];
        const float* w1 = &sH2[(g+16)*W64P];
        const float* w2 = &sH2[(g+32)*W64P];
        const float* w3 = &sH2[(g+48)*W64P];
        const float* a  = &bufA[bp*ABUF];
#pragma unroll
        for (int k = 0; k < 64; k += 4){
          const float4 h = *(const float4*)(a+k);
          a0 += dot4(*(const float4*)(w0+k), h);
          a1 += dot4(*(const float4*)(w1+k), h);
          a2 += dot4(*(const float4*)(w2+k), h);
          a3 += dot4(*(const float4*)(w3+k), h);
        }
        bufB[bp*ABUF + g    ] = frelu(a0);
        bufB[bp*ABUF + g+16 ] = frelu(a1);
        bufB[bp*ABUF + g+32 ] = frelu(a2);
        bufB[bp*ABUF + g+48 ] = frelu(a3);
      }
      LDS_FENCE();

      // H3: bufB -> bufA
      {
        float a0 = sHB3[g], a1 = sHB3[g+16], a2 = sHB3[g+32], a3 = sHB3[g+48];
        const float* w0 = &sH3[(g    )*W64P];
        const float* w1 = &sH3[(g+16)*W64P];
        const float* w2 = &sH3[(g+32)*W64P];
        const float* w3 = &sH3[(g+48)*W64P];
        const float* a  = &bufB[bp*ABUF];
#pragma unroll
        for (int k = 0; k < 64; k += 4){
          const float4 h = *(const float4*)(a+k);
          a0 += dot4(*(const float4*)(w0+k), h);
          a1 += dot4(*(const float4*)(w1+k), h);
          a2 += dot4(*(const float4*)(w2+k), h);
          a3 += dot4(*(const float4*)(w3+k), h);
        }
        bufA[bp*ABUF + g    ] = frelu(a0);
        bufA[bp*ABUF + g+16 ] = frelu(a1);
        bufA[bp*ABUF + g+32 ] = frelu(a2);
        bufA[bp*ABUF + g+48 ] = frelu(a3);
      }
      LDS_FENCE();

      // G += c * h3
      {
        const float c = carr[bp];
        Greg0 += c * bufA[bp*ABUF + g    ];
        Greg1 += c * bufA[bp*ABUF + g+16 ];
        Greg2 += c * bufA[bp*ABUF + g+32 ];
        Greg3 += c * bufA[bp*ABUF + g+48 ];
      }
    } // steps

    // ---------------- maturity-m epilogue ----------------
    Gst[bp*GSTP + m*64 + g    ] = Greg0;
    Gst[bp*GSTP + m*64 + g+16 ] = Greg1;
    Gst[bp*GSTP + m*64 + g+32 ] = Greg2;
    Gst[bp*GSTP + m*64 + g+48 ] = Greg3;
    if (g == 0) Cst[m*NPATH + bp] = Cacc;
    LDS_FENCE();

    {
      const float discm = (float)exp(-0.05*(2.0/96.0)*(double)(PERS*(m+1)));
      const float Sfin  = Sarr[bp];
#pragma unroll 1
      for (int k = g; k < NK; k += 16){
        const int r = k*4 + m;
        float acc = 0.f;
#pragma unroll 1
        for (int q = 0; q <= m; ++q){
          const float* w  = hW4 + (size_t)(q*804 + r)*64;
          const float* gv = &Gst[bp*GSTP + q*64];
          float a = hb4[q*804 + r] * Cst[q*NPATH + bp];
#pragma unroll
          for (int kk = 0; kk < 64; kk += 4)
            a += dot4(*(const float4*)(w+kk), *(const float4*)(gv+kk));
          acc += a;
        }
        const float pay = discm * frelu(Sfin - strikes[k]) - acc;
        float s1 = pay, s2 = pay*pay;
        s1 += __shfl_down(s1, 2, 4); s1 += __shfl_down(s1, 1, 4);
        s2 += __shfl_down(s2, 2, 4); s2 += __shfl_down(s2, 1, 4);
        if (p == 0){
          atomicAdd(&psum[k*2    ], s1);
          atomicAdd(&psum[k*2 + 1], s2);
        }
      }
    }
    __syncthreads();   // (c) psum complete
    for (int k = tid; k < NK; k += TPB){
      part1[(m*NK + k)*NBLOCKS + blockIdx.x] = psum[k*2];
      part2[(m*NK + k)*NBLOCKS + blockIdx.x] = psum[k*2+1];
    }
  } // maturities
}

__global__ __launch_bounds__(256)
void finalize_kernel(const float* __restrict__ part1,
                     const float* __restrict__ part2,
                     float* __restrict__ out)
{
  const int j   = blockIdx.x;          // j = m*NK + k
  const int m   = j / NK, k = j % NK;
  const int tid = threadIdx.x;
  double s1 = (double)part1[(size_t)j*NBLOCKS + tid];
  double s2 = (double)part2[(size_t)j*NBLOCKS + tid];
#pragma unroll
  for (int d = 32; d > 0; d >>= 1){
    s1 += __shfl_down(s1, d, 64);
    s2 += __shfl_down(s2, d, 64);
  }
  __shared__ double r1[4], r2[4];
  if ((tid & 63) == 0){ r1[tid>>6] = s1; r2[tid>>6] = s2; }
  __syncthreads();
  if (tid == 0){
    const double t1 = r1[0]+r1[1]+r1[2]+r1[3];
    const double t2 = r2[0]+r2[1]+r2[2]+r2[3];
    const double mean = t1 / 8192.0;
    const double var  = (t2 - t1*t1/8192.0) / 8191.0;   // ddof=1
    out[k*NMAT + m]            = (float)mean;
    out[NK*NMAT + k*NMAT + m]  = (float)var;
  }
}

extern "C" void kernel_launch(void* const* d_in, const int* in_sizes, int n_in,
                              void* d_out, int out_size, void* d_ws, size_t ws_size,
                              hipStream_t stream)
{
  (void)in_sizes; (void)n_in; (void)out_size; (void)ws_size;
  const float* nW0 = (const float*)d_in[0];
  const float* nb0 = (const float*)d_in[1];
  const float* nW1 = (const float*)d_in[2];
  const float* nb1 = (const float*)d_in[3];
  const float* nW2 = (const float*)d_in[4];
  const float* nb2 = (const float*)d_in[5];
  const float* nW3 = (const float*)d_in[6];
  const float* nb3 = (const float*)d_in[7];
  const float* hW0 = (const float*)d_in[8];
  const float* hb0 = (const float*)d_in[9];
  const float* hW1 = (const float*)d_in[10];
  const float* hb1 = (const float*)d_in[11];
  const float* hW2 = (const float*)d_in[12];
  const float* hb2 = (const float*)d_in[13];
  const float* hW3 = (const float*)d_in[14];
  const float* hb3 = (const float*)d_in[15];
  const float* hW4 = (const float*)d_in[16];
  const float* hb4 = (const float*)d_in[17];
  const float* rho = (const float*)d_in[18];
  const float* V0  = (const float*)d_in[19];
  const float* strikes = (const float*)d_in[20];
  const float* noise1  = (const float*)d_in[21];
  const float* noise2  = (const float*)d_in[22];

  float* part1 = (float*)d_ws;
  float* part2 = part1 + (size_t)NMAT*NK*NBLOCKS;

  sde_kernel<<<NBLOCKS, TPB, 0, stream>>>(nW0, nb0, nW1, nb1, nW2, nb2, nW3, nb3,
                                          hW0, hb0, hW1, hb1, hW2, hb2, hW3, hb3,
                                          hW4, hb4, rho, V0, strikes, noise1, noise2,
                                          part1, part2);

  finalize_kernel<<<NMAT*NK, 256, 0, stream>>>(part1, part2, (float*)d_out);
}

// Round 4
// 1297.092 us; speedup vs baseline: 16.8257x; 1.0118x over previous
//
#include <hip/hip_runtime.h>
#include <math.h>

#define TPB      256
#define NPATH    32       // paths per block: 4 waves x 8 paths
#define NBLOCKS  256
#define BATCHN   8192
#define NMAT     4
#define PERS     24
#define NK       201
#define BSTR     104      // activation row stride in halves (208B; dword-bank 20p%32 distinct)

typedef _Float16 f16;
typedef _Float16 f16x8 __attribute__((ext_vector_type(8)));

__device__ __forceinline__ float frelu(float x){ return x > 0.f ? x : 0.f; }

// 8-wide f16 dot with f32 accumulate (v_dot2_f32_f16 x4)
__device__ __forceinline__ float dot8h(const f16x8 a, const f16x8 w, float acc){
#if __has_builtin(__builtin_amdgcn_fdot2)
  acc = __builtin_amdgcn_fdot2(__builtin_shufflevector(a,a,0,1), __builtin_shufflevector(w,w,0,1), acc, false);
  acc = __builtin_amdgcn_fdot2(__builtin_shufflevector(a,a,2,3), __builtin_shufflevector(w,w,2,3), acc, false);
  acc = __builtin_amdgcn_fdot2(__builtin_shufflevector(a,a,4,5), __builtin_shufflevector(w,w,4,5), acc, false);
  acc = __builtin_amdgcn_fdot2(__builtin_shufflevector(a,a,6,7), __builtin_shufflevector(w,w,6,7), acc, false);
#else
#pragma unroll
  for (int i = 0; i < 8; ++i) acc = fmaf((float)a[i], (float)w[i], acc);
#endif
  return acc;
}

template<int N> struct IC { static constexpr int v = N; };

// Intra-wave LDS write->read fence (paths are wave-private; no cross-wave deps in step loop)
#define LDS_FENCE() asm volatile("s_waitcnt lgkmcnt(0)" ::: "memory")

__global__ __launch_bounds__(TPB, 2)
void sde_kernel(const float* __restrict__ nW0, const float* __restrict__ nb0,
                const float* __restrict__ nW1, const float* __restrict__ nb1,
                const float* __restrict__ nW2, const float* __restrict__ nb2,
                const float* __restrict__ nW3, const float* __restrict__ nb3,
                const float* __restrict__ hW0, const float* __restrict__ hb0,
                const float* __restrict__ hW1, const float* __restrict__ hb1,
                const float* __restrict__ hW2, const float* __restrict__ hb2,
                const float* __restrict__ hW3, const float* __restrict__ hb3,
                const float* __restrict__ hW4, const float* __restrict__ hb4,
                const float* __restrict__ rho, const float* __restrict__ V0,
                const float* __restrict__ strikes,
                const float* __restrict__ noise1, const float* __restrict__ noise2,
                float* __restrict__ part1, float* __restrict__ part2)
{
  // ---- maturity-m weights (f16 where hot) ----
  __shared__ __align__(16) float sW0[96*4];        // [wt,wS,wV,bias] per drift-L0 row
  __shared__ __align__(16) f16   sW1h[96*40];
  __shared__ __align__(16) f16   sW2h[96*40];
  __shared__ __align__(16) float sB1[96];
  __shared__ __align__(16) float sB2[96];
  __shared__ __align__(16) f16   sW3h[3*40];
  __shared__            float sB3v[4];
  __shared__ __align__(16) float sH0[128];
  __shared__ __align__(16) float sHB0[64];
  __shared__ __align__(16) f16   sH1h[64*72];
  __shared__ __align__(16) f16   sH2h[64*72];
  __shared__ __align__(16) f16   sH3h[64*72];
  __shared__ __align__(16) float sHB1[64];
  __shared__ __align__(16) float sHB2[64];
  __shared__ __align__(16) float sHB3[64];
  // ---- per-path state / activations (f16 ping-pong) ----
  __shared__ __align__(16) f16   buf0h[NPATH*BSTR];
  __shared__ __align__(16) f16   buf1h[NPATH*BSTR];
  __shared__ float Sarr[NPATH], Varr[NPATH], carr[NPATH];
  __shared__ float rawL[3*NPATH];
  __shared__ float CstL[NMAT*NPATH];
  __shared__ float psum[NK*2];
  __shared__ float strikesL[NK];

  const int tid   = threadIdx.x;
  const int lane  = tid & 63;
  const int wave  = tid >> 6;
  const int p     = lane & 7;           // path within wave
  const int g     = lane >> 3;          // row-group 0..7
  const int bp    = wave*8 + p;         // block-path 0..31
  const int gpath = blockIdx.x * NPATH + bp;

  const float DTf = (float)(2.0/96.0);
  const float SDT = 0.14433756729740643f;          // sqrt(DT)
  const float DFf = (float)exp(-0.05 * 2.0 / 96.0);
  const float rho_s = rho[0];
  const float rt1m  = sqrtf(1.f - rho_s*rho_s);

  if (tid < NK) strikesL[tid] = strikes[tid];
  if (g == 0){ Sarr[bp] = 100.f; Varr[bp] = V0[0]; }

  float Gq[NMAT][8];   // per-lane G rows g+8j, per period; fully static indexing

  auto maturity = [&](auto MC){
    constexpr int m = decltype(MC)::v;
    __syncthreads();   // prior maturity fully done (part-writes read psum; weights reusable)

    // ---------------- stage maturity-m weights ----------------
    for (int i = tid; i < 96*4; i += TPB){
      const int r = i >> 2, c = i & 3, n = r >> 5, o = r & 31;
      sW0[i] = (c < 3) ? nW0[n*384 + m*96 + o*3 + c] : nb0[n*128 + m*32 + o];
    }
    for (int i = tid; i < 3072; i += TPB){
      const int r = i >> 5, c = i & 31, n = r >> 5, o = r & 31;
      sW1h[r*40 + c] = (f16)nW1[n*4096 + m*1024 + o*32 + c];
      sW2h[r*40 + c] = (f16)nW2[n*4096 + m*1024 + o*32 + c];
    }
    for (int i = tid; i < 96; i += TPB){
      const int n = i >> 5, o = i & 31;
      sB1[i] = nb1[n*128 + m*32 + o];
      sB2[i] = nb2[n*128 + m*32 + o];
      sW3h[(i>>5)*40 + (i&31)] = (f16)nW3[n*128 + m*32 + o];
    }
    if (tid < 3) sB3v[tid] = nb3[tid*4 + m];
    for (int i = tid; i < 128; i += TPB) sH0[i] = hW0[m*128 + i];
    for (int i = tid; i < 64; i += TPB){
      sHB0[i] = hb0[m*64+i]; sHB1[i] = hb1[m*64+i];
      sHB2[i] = hb2[m*64+i]; sHB3[i] = hb3[m*64+i];
    }
    for (int i = tid; i < 4096; i += TPB){
      const int r = i >> 6, c = i & 63;
      sH1h[r*72 + c] = (f16)hW1[m*4096 + i];
      sH2h[r*72 + c] = (f16)hW2[m*4096 + i];
      sH3h[r*72 + c] = (f16)hW3[m*4096 + i];
    }
    for (int i = tid; i < NK*2; i += TPB) psum[i] = 0.f;
    __syncthreads();   // weights + psum ready

#pragma unroll
    for (int j = 0; j < 8; ++j) Gq[m][j] = 0.f;
    float Cacc = 0.f;

    // ---------------- 24 steps, wave-independent ----------------
#pragma unroll 1
    for (int s = 0; s < PERS; ++s){
      const int   gstep = m*PERS + s;
      const float t     = (float)gstep * DTf;

      float n1r = 0.f, n2r = 0.f;
      if (g == 0){
        n1r = noise1[(size_t)gstep*BATCHN + gpath];
        n2r = noise2[(size_t)gstep*BATCHN + gpath];
      }
      const float S = Sarr[bp], V = Varr[bp];

      // D0: 96 rows -> buf0
#pragma unroll
      for (int j = 0; j < 12; ++j){
        const int r = g + 8*j;
        const float4 w = *(const float4*)&sW0[r*4];
        buf0h[bp*BSTR + r] = (f16)frelu(w.x*t + w.y*S + w.z*V + w.w);
      }
      LDS_FENCE();

      // D1: buf0 -> buf1
      {
        float acc[12];
#pragma unroll
        for (int j = 0; j < 12; ++j) acc[j] = sB1[g + 8*j];
#pragma unroll
        for (int nt = 0; nt < 3; ++nt){
#pragma unroll
          for (int kc = 0; kc < 4; ++kc){
            const f16x8 av = *(const f16x8*)&buf0h[bp*BSTR + nt*32 + kc*8];
#pragma unroll
            for (int jj = 0; jj < 4; ++jj){
              const int j = nt*4 + jj;
              const f16x8 wv = *(const f16x8*)&sW1h[(g + 8*j)*40 + kc*8];
              acc[j] = dot8h(av, wv, acc[j]);
            }
          }
        }
#pragma unroll
        for (int j = 0; j < 12; ++j)
          buf1h[bp*BSTR + g + 8*j] = (f16)frelu(acc[j]);
      }
      LDS_FENCE();

      // D2: buf1 -> buf0
      {
        float acc[12];
#pragma unroll
        for (int j = 0; j < 12; ++j) acc[j] = sB2[g + 8*j];
#pragma unroll
        for (int nt = 0; nt < 3; ++nt){
#pragma unroll
          for (int kc = 0; kc < 4; ++kc){
            const f16x8 av = *(const f16x8*)&buf1h[bp*BSTR + nt*32 + kc*8];
#pragma unroll
            for (int jj = 0; jj < 4; ++jj){
              const int j = nt*4 + jj;
              const f16x8 wv = *(const f16x8*)&sW2h[(g + 8*j)*40 + kc*8];
              acc[j] = dot8h(av, wv, acc[j]);
            }
          }
        }
#pragma unroll
        for (int j = 0; j < 12; ++j)
          buf0h[bp*BSTR + g + 8*j] = (f16)frelu(acc[j]);
      }
      LDS_FENCE();

      // D3: 3 scalar outputs
      if (g < 3){
        float acc = sB3v[g];
#pragma unroll
        for (int kc = 0; kc < 4; ++kc){
          const f16x8 av = *(const f16x8*)&buf0h[bp*BSTR + g*32 + kc*8];
          const f16x8 wv = *(const f16x8*)&sW3h[g*40 + kc*8];
          acc = dot8h(av, wv, acc);
        }
        rawL[g*NPATH + bp] = acc;
      }
      LDS_FENCE();

      // SDE update (g==0 lane per path)
      if (g == 0){
        const float r0 = rawL[bp], r1 = rawL[NPATH+bp], r2 = rawL[2*NPATH+bp];
        const float sigS = r0/(1.f+fabsf(r0)*SDT);
        const float bV   = r1/(1.f+fabsf(r1)*SDT);
        const float sigV = r2/(1.f+fabsf(r2)*SDT);
        const float sr = S*0.05f;
        const float bS = sr/(1.f+fabsf(sr)*SDT);
        const float dW = SDT*n2r;
        const float dB = rho_s*dW + rt1m*SDT*n1r;
        const float c  = DFf*S*sigS*dW;
        carr[bp] = c;  Cacc += c;
        Sarr[bp] = S + bS*DTf + sigS*dB;
        Varr[bp] = frelu(V + bV*DTf + sigV*dW);
      }

      // H0: 64 rows (pre-update S from register) -> buf1
#pragma unroll
      for (int j = 0; j < 8; ++j){
        const int o = g + 8*j;
        buf1h[bp*BSTR + o] = (f16)frelu(sH0[o*2]*t + sH0[o*2+1]*S + sHB0[o]);
      }
      LDS_FENCE();

      // H1: buf1 -> buf0
      {
        float acc[8];
#pragma unroll
        for (int j = 0; j < 8; ++j) acc[j] = sHB1[g + 8*j];
#pragma unroll
        for (int kc = 0; kc < 8; ++kc){
          const f16x8 av = *(const f16x8*)&buf1h[bp*BSTR + kc*8];
#pragma unroll
          for (int j = 0; j < 8; ++j){
            const f16x8 wv = *(const f16x8*)&sH1h[(g + 8*j)*72 + kc*8];
            acc[j] = dot8h(av, wv, acc[j]);
          }
        }
#pragma unroll
        for (int j = 0; j < 8; ++j)
          buf0h[bp*BSTR + g + 8*j] = (f16)frelu(acc[j]);
      }
      LDS_FENCE();

      // H2: buf0 -> buf1
      {
        float acc[8];
#pragma unroll
        for (int j = 0; j < 8; ++j) acc[j] = sHB2[g + 8*j];
#pragma unroll
        for (int kc = 0; kc < 8; ++kc){
          const f16x8 av = *(const f16x8*)&buf0h[bp*BSTR + kc*8];
#pragma unroll
          for (int j = 0; j < 8; ++j){
            const f16x8 wv = *(const f16x8*)&sH2h[(g + 8*j)*72 + kc*8];
            acc[j] = dot8h(av, wv, acc[j]);
          }
        }
#pragma unroll
        for (int j = 0; j < 8; ++j)
          buf1h[bp*BSTR + g + 8*j] = (f16)frelu(acc[j]);
      }
      LDS_FENCE();

      // H3: buf1 -> buf0
      {
        float acc[8];
#pragma unroll
        for (int j = 0; j < 8; ++j) acc[j] = sHB3[g + 8*j];
#pragma unroll
        for (int kc = 0; kc < 8; ++kc){
          const f16x8 av = *(const f16x8*)&buf1h[bp*BSTR + kc*8];
#pragma unroll
          for (int j = 0; j < 8; ++j){
            const f16x8 wv = *(const f16x8*)&sH3h[(g + 8*j)*72 + kc*8];
            acc[j] = dot8h(av, wv, acc[j]);
          }
        }
#pragma unroll
        for (int j = 0; j < 8; ++j)
          buf0h[bp*BSTR + g + 8*j] = (f16)frelu(acc[j]);
      }
      LDS_FENCE();

      // G += c * h3 (rows g+8j in registers)
      {
        const float c = carr[bp];
#pragma unroll
        for (int j = 0; j < 8; ++j)
          Gq[m][j] = fmaf(c, (float)buf0h[bp*BSTR + g + 8*j], Gq[m][j]);
      }
    } // steps

    // ---------------- epilogue for maturity m ----------------
    if (g == 0) CstL[m*NPATH + bp] = Cacc;
    LDS_FENCE();

    {
      const float discm = (float)exp(-0.05*(2.0/96.0)*(double)(PERS*(m+1)));
      const float Sfin  = Sarr[bp];
#pragma unroll 1
      for (int k = 0; k < NK; ++k){
        const int rr = k*4 + m;
        float acc = 0.f;
#pragma unroll
        for (int q = 0; q <= m; ++q){
          const float* wr = hW4 + (size_t)(q*804 + rr)*64 + g;
          float part = 0.f;
#pragma unroll
          for (int j = 0; j < 8; ++j)
            part = fmaf(wr[8*j], Gq[q][j], part);
          acc += part;
        }
        // reduce over row-groups g (bits 3..5)
        acc += __shfl_xor(acc, 8); acc += __shfl_xor(acc, 16); acc += __shfl_xor(acc, 32);
#pragma unroll
        for (int q = 0; q <= m; ++q)
          acc = fmaf(hb4[q*804 + rr], CstL[q*NPATH + bp], acc);
        const float pay = discm * frelu(Sfin - strikesL[k]) - acc;
        float s1 = pay, s2 = pay*pay;
        // reduce over paths p (bits 0..2)
        s1 += __shfl_xor(s1,1); s1 += __shfl_xor(s1,2); s1 += __shfl_xor(s1,4);
        s2 += __shfl_xor(s2,1); s2 += __shfl_xor(s2,2); s2 += __shfl_xor(s2,4);
        if (lane == 0){
          atomicAdd(&psum[k*2    ], s1);
          atomicAdd(&psum[k*2 + 1], s2);
        }
      }
    }
    __syncthreads();   // psum complete across waves
    for (int k = tid; k < NK; k += TPB){
      part1[(m*NK + k)*NBLOCKS + blockIdx.x] = psum[k*2];
      part2[(m*NK + k)*NBLOCKS + blockIdx.x] = psum[k*2+1];
    }
  };

  maturity(IC<0>{});
  maturity(IC<1>{});
  maturity(IC<2>{});
  maturity(IC<3>{});
}

__global__ __launch_bounds__(256)
void finalize_kernel(const float* __restrict__ part1,
                     const float* __restrict__ part2,
                     float* __restrict__ out)
{
  const int j   = blockIdx.x;          // j = m*NK + k
  const int m   = j / NK, k = j % NK;
  const int tid = threadIdx.x;
  double s1 = (double)part1[(size_t)j*NBLOCKS + tid];
  double s2 = (double)part2[(size_t)j*NBLOCKS + tid];
#pragma unroll
  for (int d = 32; d > 0; d >>= 1){
    s1 += __shfl_down(s1, d, 64);
    s2 += __shfl_down(s2, d, 64);
  }
  __shared__ double r1[4], r2[4];
  if ((tid & 63) == 0){ r1[tid>>6] = s1; r2[tid>>6] = s2; }
  __syncthreads();
  if (tid == 0){
    const double t1 = r1[0]+r1[1]+r1[2]+r1[3];
    const double t2 = r2[0]+r2[1]+r2[2]+r2[3];
    const double mean = t1 / 8192.0;
    const double var  = (t2 - t1*t1/8192.0) / 8191.0;   // ddof=1
    out[k*NMAT + m]            = (float)mean;
    out[NK*NMAT + k*NMAT + m]  = (float)var;
  }
}

extern "C" void kernel_launch(void* const* d_in, const int* in_sizes, int n_in,
                              void* d_out, int out_size, void* d_ws, size_t ws_size,
                              hipStream_t stream)
{
  (void)in_sizes; (void)n_in; (void)out_size; (void)ws_size;
  const float* nW0 = (const float*)d_in[0];
  const float* nb0 = (const float*)d_in[1];
  const float* nW1 = (const float*)d_in[2];
  const float* nb1 = (const float*)d_in[3];
  const float* nW2 = (const float*)d_in[4];
  const float* nb2 = (const float*)d_in[5];
  const float* nW3 = (const float*)d_in[6];
  const float* nb3 = (const float*)d_in[7];
  const float* hW0 = (const float*)d_in[8];
  const float* hb0 = (const float*)d_in[9];
  const float* hW1 = (const float*)d_in[10];
  const float* hb1 = (const float*)d_in[11];
  const float* hW2 = (const float*)d_in[12];
  const float* hb2 = (const float*)d_in[13];
  const float* hW3 = (const float*)d_in[14];
  const float* hb3 = (const float*)d_in[15];
  const float* hW4 = (const float*)d_in[16];
  const float* hb4 = (const float*)d_in[17];
  const float* rho = (const float*)d_in[18];
  const float* V0  = (const float*)d_in[19];
  const float* strikes = (const float*)d_in[20];
  const float* noise1  = (const float*)d_in[21];
  const float* noise2  = (const float*)d_in[22];

  float* part1 = (float*)d_ws;
  float* part2 = part1 + (size_t)NMAT*NK*NBLOCKS;

  sde_kernel<<<NBLOCKS, TPB, 0, stream>>>(nW0, nb0, nW1, nb1, nW2, nb2, nW3, nb3,
                                          hW0, hb0, hW1, hb1, hW2, hb2, hW3, hb3,
                                          hW4, hb4, rho, V0, strikes, noise1, noise2,
                                          part1, part2);

  finalize_kernel<<<NMAT*NK, 256, 0, stream>>>(part1, part2, (float*)d_out);
}

// Round 5
// 916.402 us; speedup vs baseline: 23.8154x; 1.4154x over previous
//
#include <hip/hip_runtime.h>
#include <math.h>

#define TPB      64
#define NBLOCKS  512
#define PPB      16      // paths per block (= per wave)
#define BATCHN   8192
#define NMAT     4
#define PERS     24
#define NK       201

typedef _Float16 f16;
typedef _Float16 f16x4 __attribute__((ext_vector_type(4)));
typedef _Float16 f16x8 __attribute__((ext_vector_type(8)));
typedef float    f32x4 __attribute__((ext_vector_type(4)));

template<int N> struct IC { static constexpr int v = N; };

// single wave per block: lgkmcnt(0) orders LDS write->read (no barrier needed)
#define LDS_FENCE() asm volatile("s_waitcnt lgkmcnt(0)" ::: "memory")

__device__ __forceinline__ f16x8 relu8(f16x8 v){
#pragma unroll
  for (int i = 0; i < 8; ++i) v[i] = (v[i] > (f16)0.f) ? v[i] : (f16)0.f;
  return v;
}

__global__ __launch_bounds__(TPB, 1)
void sde_kernel(const float* __restrict__ nW0, const float* __restrict__ nb0,
                const float* __restrict__ nW1, const float* __restrict__ nb1,
                const float* __restrict__ nW2, const float* __restrict__ nb2,
                const float* __restrict__ nW3, const float* __restrict__ nb3,
                const float* __restrict__ hW0, const float* __restrict__ hb0,
                const float* __restrict__ hW1, const float* __restrict__ hb1,
                const float* __restrict__ hW2, const float* __restrict__ hb2,
                const float* __restrict__ hW3, const float* __restrict__ hb3,
                const float* __restrict__ hW4, const float* __restrict__ hb4,
                const float* __restrict__ rho, const float* __restrict__ V0,
                const float* __restrict__ strikes,
                const float* __restrict__ noise1, const float* __restrict__ noise2,
                float* __restrict__ part1, float* __restrict__ part2)
{
  // drift L1/L2 A-tiles: [layer][tile t6=n*2+mt][row 16][40 pad] halves
  __shared__ __align__(16) f16   aD[2*6*640];
  __shared__ __align__(16) f16   w0h[384];        // [net][comp(wt,wS,wV,b)][32 rows]
  __shared__ __align__(16) f16   wh0[192];        // [comp(wt,wS,b)][64 rows]
  __shared__ __align__(16) float w3L[96];         // [net][32 rows]
  __shared__ __align__(16) f16   bD1[96], bD2[96], bH[192];
  __shared__ __align__(16) f16   bb0[PPB*120], bb1[PPB*120];   // bounce buffers
  __shared__ __align__(16) float Gsave[4*PPB*68];

  const int lane = threadIdx.x;        // 0..63
  const int P    = lane & 15;          // path (MFMA col)
  const int G    = lane >> 4;          // lane group (k/row quadrant)
  const int gpath = blockIdx.x * PPB + P;

  const float DTf = (float)(2.0/96.0);
  const float SDT = 0.14433756729740643f;          // sqrt(DT)
  const float DFf = (float)exp(-0.05 * 2.0 / 96.0);
  const float rho_s = rho[0];
  const float rt1m  = sqrtf(1.f - rho_s*rho_s);

  float S = 100.f, V = V0[0];
  float Cq[4];
  float Gacc[16];

  auto maturity = [&](auto MC){
    constexpr int m = decltype(MC)::v;

    // ---------------- stage maturity-m weights ----------------
    for (int i = lane; i < 3072; i += TPB){
      const int t6 = i >> 9, rem = i & 511, rr = rem >> 5, k = i & 31;
      const int n = t6 >> 1, o = ((t6 & 1) << 4) + rr;
      const int src = (((n*4+m)*32)+o)*32 + k;
      aD[       t6*640 + rr*40 + k] = (f16)nW1[src];
      aD[3840 + t6*640 + rr*40 + k] = (f16)nW2[src];
    }
    for (int i = lane; i < 384; i += TPB){
      const int n = i >> 7, c = (i >> 5) & 3, o = i & 31;
      w0h[i] = (c < 3) ? (f16)nW0[(((n*4+m)*32)+o)*3 + c]
                       : (f16)nb0[((n*4+m)*32)+o];
    }
    for (int i = lane; i < 192; i += TPB){
      const int c = i >> 6, o = i & 63;
      const float v = (c==0) ? hW0[m*128 + o*2]
                    : (c==1) ? hW0[m*128 + o*2 + 1]
                             : hb0[m*64 + o];
      wh0[i] = (f16)v;
    }
    for (int i = lane; i < 96; i += TPB){
      const int n = i >> 5, o = i & 31;
      w3L[i] = nW3[((n*4+m)*32)+o];
      bD1[i] = (f16)nb1[((n*4+m)*32)+o];
      bD2[i] = (f16)nb2[((n*4+m)*32)+o];
    }
    for (int i = lane; i < 64; i += TPB){
      bH[i]       = (f16)hb1[m*64+i];
      bH[64 + i]  = (f16)hb2[m*64+i];
      bH[128 + i] = (f16)hb3[m*64+i];
    }
    const float b30 = nb3[m], b31 = nb3[4+m], b32 = nb3[8+m];

    // hedge A-fragments in registers (reused 24 steps)
    f16x8 aH[3][4][2];
#pragma unroll
    for (int L = 0; L < 3; ++L){
      const float* W = (L==0) ? hW1 : (L==1) ? hW2 : hW3;
#pragma unroll
      for (int mt = 0; mt < 4; ++mt)
#pragma unroll
      for (int kt = 0; kt < 2; ++kt){
        const float* src = W + m*4096 + (16*mt + P)*64 + kt*32 + G*8;
        const float4 v0 = *(const float4*)(src);
        const float4 v1 = *(const float4*)(src + 4);
        f16x8 a;
        a[0]=(f16)v0.x; a[1]=(f16)v0.y; a[2]=(f16)v0.z; a[3]=(f16)v0.w;
        a[4]=(f16)v1.x; a[5]=(f16)v1.y; a[6]=(f16)v1.z; a[7]=(f16)v1.w;
        aH[L][mt][kt] = a;
      }
    }
    LDS_FENCE();   // staging visible to whole wave

#pragma unroll
    for (int j = 0; j < 16; ++j) Gacc[j] = 0.f;
    float Cacc = 0.f;

    // ---------------- 24 steps ----------------
#pragma unroll 1
    for (int s = 0; s < PERS; ++s){
      const int   gstep = m*PERS + s;
      const float t     = (float)gstep * DTf;
      const float n1r = noise1[(size_t)gstep*BATCHN + gpath];
      const float n2r = noise2[(size_t)gstep*BATCHN + gpath];
      const f16 th = (f16)t, Sh = (f16)S, Vh = (f16)V;

      // ---- drift L0 (direct into B-frags, packed f16)
      f16x8 bfr[3];
#pragma unroll
      for (int n = 0; n < 3; ++n){
        const f16x8 wt = *(const f16x8*)&w0h[n*128 +       G*8];
        const f16x8 ws = *(const f16x8*)&w0h[n*128 + 32  + G*8];
        const f16x8 wv = *(const f16x8*)&w0h[n*128 + 64  + G*8];
        const f16x8 bz = *(const f16x8*)&w0h[n*128 + 96  + G*8];
        bfr[n] = relu8(wt*th + ws*Sh + wv*Vh + bz);
      }

      // ---- drift L1 (MFMA) -> bounce bb0
#pragma unroll
      for (int t6 = 0; t6 < 6; ++t6){
        const f16x8 a  = *(const f16x8*)&aD[t6*640 + P*40 + G*8];
        const f16x4 b4 = *(const f16x4*)&bD1[t6*16 + 4*G];
        f32x4 acc = { (float)b4[0], (float)b4[1], (float)b4[2], (float)b4[3] };
        acc = __builtin_amdgcn_mfma_f32_16x16x32_f16(a, bfr[t6>>1], acc, 0, 0, 0);
        f16x4 o;
        o[0]=(f16)fmaxf(acc[0],0.f); o[1]=(f16)fmaxf(acc[1],0.f);
        o[2]=(f16)fmaxf(acc[2],0.f); o[3]=(f16)fmaxf(acc[3],0.f);
        *(f16x4*)&bb0[P*120 + t6*16 + 4*G] = o;
      }
      LDS_FENCE();

      // ---- drift L2 (MFMA), C stays in regs
      f16x8 bl[3];
#pragma unroll
      for (int n = 0; n < 3; ++n)
        bl[n] = *(const f16x8*)&bb0[P*120 + n*32 + G*8];
      f32x4 c2[6];
#pragma unroll
      for (int t6 = 0; t6 < 6; ++t6){
        const f16x8 a  = *(const f16x8*)&aD[3840 + t6*640 + P*40 + G*8];
        const f16x4 b4 = *(const f16x4*)&bD2[t6*16 + 4*G];
        f32x4 acc = { (float)b4[0], (float)b4[1], (float)b4[2], (float)b4[3] };
        c2[t6] = __builtin_amdgcn_mfma_f32_16x16x32_f16(a, bl[t6>>1], acc, 0, 0, 0);
      }

      // ---- drift L3: in-register partial dots + cross-group shuffle reduce
      float pr0 = 0.f, pr1 = 0.f, pr2 = 0.f;
#pragma unroll
      for (int t6 = 0; t6 < 6; ++t6){
        const f32x4 w4 = *(const f32x4*)&w3L[(t6>>1)*32 + (t6&1)*16 + 4*G];
        const float p = w4[0]*fmaxf(c2[t6][0],0.f) + w4[1]*fmaxf(c2[t6][1],0.f)
                      + w4[2]*fmaxf(c2[t6][2],0.f) + w4[3]*fmaxf(c2[t6][3],0.f);
        if (t6 < 2) pr0 += p; else if (t6 < 4) pr1 += p; else pr2 += p;
      }
      pr0 += __shfl_xor(pr0, 16); pr0 += __shfl_xor(pr0, 32);
      pr1 += __shfl_xor(pr1, 16); pr1 += __shfl_xor(pr1, 32);
      pr2 += __shfl_xor(pr2, 16); pr2 += __shfl_xor(pr2, 32);
      const float r0 = pr0 + b30, r1 = pr1 + b31, r2 = pr2 + b32;

      // ---- SDE update (replicated across G-lanes; uses OLD S below)
      const float sigS = r0/(1.f + fabsf(r0)*SDT);
      const float bV   = r1/(1.f + fabsf(r1)*SDT);
      const float sigV = r2/(1.f + fabsf(r2)*SDT);
      const float sr   = S*0.05f;
      const float bS   = sr/(1.f + fabsf(sr)*SDT);
      const float dW   = SDT*n2r;
      const float dB   = rho_s*dW + rt1m*SDT*n1r;
      const float c    = DFf*S*sigS*dW;
      Cacc += c;
      const float Snew = S + bS*DTf + sigS*dB;
      const float Vnew = fmaxf(V + bV*DTf + sigV*dW, 0.f);

      // ---- hedge L0 (direct into B-frags; pre-update S)
      f16x8 bh0, bh1;
      {
        const f16x8 wt0 = *(const f16x8*)&wh0[       G*8];
        const f16x8 ws0 = *(const f16x8*)&wh0[ 64 +  G*8];
        const f16x8 bz0 = *(const f16x8*)&wh0[128 +  G*8];
        bh0 = relu8(wt0*th + ws0*Sh + bz0);
        const f16x8 wt1 = *(const f16x8*)&wh0[ 32 +  G*8];
        const f16x8 ws1 = *(const f16x8*)&wh0[ 96 +  G*8];
        const f16x8 bz1 = *(const f16x8*)&wh0[160 +  G*8];
        bh1 = relu8(wt1*th + ws1*Sh + bz1);
      }

      // ---- hedge L1 -> bb1
#pragma unroll
      for (int mt = 0; mt < 4; ++mt){
        const f16x4 b4 = *(const f16x4*)&bH[mt*16 + 4*G];
        f32x4 acc = { (float)b4[0], (float)b4[1], (float)b4[2], (float)b4[3] };
        acc = __builtin_amdgcn_mfma_f32_16x16x32_f16(aH[0][mt][0], bh0, acc, 0, 0, 0);
        acc = __builtin_amdgcn_mfma_f32_16x16x32_f16(aH[0][mt][1], bh1, acc, 0, 0, 0);
        f16x4 o;
        o[0]=(f16)fmaxf(acc[0],0.f); o[1]=(f16)fmaxf(acc[1],0.f);
        o[2]=(f16)fmaxf(acc[2],0.f); o[3]=(f16)fmaxf(acc[3],0.f);
        *(f16x4*)&bb1[P*120 + mt*16 + 4*G] = o;
      }
      LDS_FENCE();
      f16x8 x0 = *(const f16x8*)&bb1[P*120 +      G*8];
      f16x8 x1 = *(const f16x8*)&bb1[P*120 + 32 + G*8];

      // ---- hedge L2 -> bb0
#pragma unroll
      for (int mt = 0; mt < 4; ++mt){
        const f16x4 b4 = *(const f16x4*)&bH[64 + mt*16 + 4*G];
        f32x4 acc = { (float)b4[0], (float)b4[1], (float)b4[2], (float)b4[3] };
        acc = __builtin_amdgcn_mfma_f32_16x16x32_f16(aH[1][mt][0], x0, acc, 0, 0, 0);
        acc = __builtin_amdgcn_mfma_f32_16x16x32_f16(aH[1][mt][1], x1, acc, 0, 0, 0);
        f16x4 o;
        o[0]=(f16)fmaxf(acc[0],0.f); o[1]=(f16)fmaxf(acc[1],0.f);
        o[2]=(f16)fmaxf(acc[2],0.f); o[3]=(f16)fmaxf(acc[3],0.f);
        *(f16x4*)&bb0[P*120 + mt*16 + 4*G] = o;
      }
      LDS_FENCE();
      x0 = *(const f16x8*)&bb0[P*120 +      G*8];
      x1 = *(const f16x8*)&bb0[P*120 + 32 + G*8];

      // ---- hedge L3 (C stays in regs) + G accumulation
#pragma unroll
      for (int mt = 0; mt < 4; ++mt){
        const f16x4 b4 = *(const f16x4*)&bH[128 + mt*16 + 4*G];
        f32x4 acc = { (float)b4[0], (float)b4[1], (float)b4[2], (float)b4[3] };
        acc = __builtin_amdgcn_mfma_f32_16x16x32_f16(aH[2][mt][0], x0, acc, 0, 0, 0);
        acc = __builtin_amdgcn_mfma_f32_16x16x32_f16(aH[2][mt][1], x1, acc, 0, 0, 0);
        Gacc[mt*4+0] += c*fmaxf(acc[0],0.f);
        Gacc[mt*4+1] += c*fmaxf(acc[1],0.f);
        Gacc[mt*4+2] += c*fmaxf(acc[2],0.f);
        Gacc[mt*4+3] += c*fmaxf(acc[3],0.f);
      }

      S = Snew; V = Vnew;
    } // steps

    // ---------------- maturity-m epilogue ----------------
    Cq[m] = Cacc;
#pragma unroll
    for (int t4 = 0; t4 < 4; ++t4){
      f32x4 gv = { Gacc[t4*4+0], Gacc[t4*4+1], Gacc[t4*4+2], Gacc[t4*4+3] };
      *(f32x4*)&Gsave[(m*PPB + P)*68 + t4*16 + 4*G] = gv;
    }
    LDS_FENCE();
    {
      const float discm = (float)exp(-0.05*(2.0/96.0)*(double)(PERS*(m+1)));
      const float Sfin  = S;
      f32x4 Gq[4][4];
#pragma unroll
      for (int q = 0; q <= m; ++q)
#pragma unroll
        for (int t4 = 0; t4 < 4; ++t4)
          Gq[q][t4] = *(const f32x4*)&Gsave[(q*PPB + P)*68 + t4*16 + 4*G];

#pragma unroll 1
      for (int k = 0; k < NK; ++k){
        const int r = k*4 + m;
        float accd = 0.f;
#pragma unroll
        for (int q = 0; q <= m; ++q){
          const float* w = hW4 + (size_t)(q*804 + r)*64 + 4*G;
#pragma unroll
          for (int t4 = 0; t4 < 4; ++t4){
            const f32x4 w4 = *(const f32x4*)(w + 16*t4);
            accd += w4[0]*Gq[q][t4][0] + w4[1]*Gq[q][t4][1]
                  + w4[2]*Gq[q][t4][2] + w4[3]*Gq[q][t4][3];
          }
        }
        accd += __shfl_xor(accd, 16); accd += __shfl_xor(accd, 32);
#pragma unroll
        for (int q = 0; q <= m; ++q) accd += hb4[q*804 + r]*Cq[q];
        const float pay = discm*fmaxf(Sfin - strikes[k], 0.f) - accd;
        float s1 = pay, s2 = pay*pay;
        s1 += __shfl_xor(s1,1); s1 += __shfl_xor(s1,2);
        s1 += __shfl_xor(s1,4); s1 += __shfl_xor(s1,8);
        s2 += __shfl_xor(s2,1); s2 += __shfl_xor(s2,2);
        s2 += __shfl_xor(s2,4); s2 += __shfl_xor(s2,8);
        if (lane == 0){
          part1[(m*NK + k)*NBLOCKS + blockIdx.x] = s1;
          part2[(m*NK + k)*NBLOCKS + blockIdx.x] = s2;
        }
      }
    }
  };

  maturity(IC<0>{});
  maturity(IC<1>{});
  maturity(IC<2>{});
  maturity(IC<3>{});
}

__global__ __launch_bounds__(256)
void finalize_kernel(const float* __restrict__ part1,
                     const float* __restrict__ part2,
                     float* __restrict__ out)
{
  const int j   = blockIdx.x;          // j = m*NK + k
  const int m   = j / NK, k = j % NK;
  const int tid = threadIdx.x;
  double s1 = (double)part1[(size_t)j*NBLOCKS + tid]
            + (double)part1[(size_t)j*NBLOCKS + 256 + tid];
  double s2 = (double)part2[(size_t)j*NBLOCKS + tid]
            + (double)part2[(size_t)j*NBLOCKS + 256 + tid];
#pragma unroll
  for (int d = 32; d > 0; d >>= 1){
    s1 += __shfl_down(s1, d, 64);
    s2 += __shfl_down(s2, d, 64);
  }
  __shared__ double r1[4], r2[4];
  if ((tid & 63) == 0){ r1[tid>>6] = s1; r2[tid>>6] = s2; }
  __syncthreads();
  if (tid == 0){
    const double t1 = r1[0]+r1[1]+r1[2]+r1[3];
    const double t2 = r2[0]+r2[1]+r2[2]+r2[3];
    const double mean = t1 / 8192.0;
    const double var  = (t2 - t1*t1/8192.0) / 8191.0;   // ddof=1
    out[k*NMAT + m]            = (float)mean;
    out[NK*NMAT + k*NMAT + m]  = (float)var;
  }
}

extern "C" void kernel_launch(void* const* d_in, const int* in_sizes, int n_in,
                              void* d_out, int out_size, void* d_ws, size_t ws_size,
                              hipStream_t stream)
{
  (void)in_sizes; (void)n_in; (void)out_size; (void)ws_size;
  const float* nW0 = (const float*)d_in[0];
  const float* nb0 = (const float*)d_in[1];
  const float* nW1 = (const float*)d_in[2];
  const float* nb1 = (const float*)d_in[3];
  const float* nW2 = (const float*)d_in[4];
  const float* nb2 = (const float*)d_in[5];
  const float* nW3 = (const float*)d_in[6];
  const float* nb3 = (const float*)d_in[7];
  const float* hW0 = (const float*)d_in[8];
  const float* hb0 = (const float*)d_in[9];
  const float* hW1 = (const float*)d_in[10];
  const float* hb1 = (const float*)d_in[11];
  const float* hW2 = (const float*)d_in[12];
  const float* hb2 = (const float*)d_in[13];
  const float* hW3 = (const float*)d_in[14];
  const float* hb3 = (const float*)d_in[15];
  const float* hW4 = (const float*)d_in[16];
  const float* hb4 = (const float*)d_in[17];
  const float* rho = (const float*)d_in[18];
  const float* V0  = (const float*)d_in[19];
  const float* strikes = (const float*)d_in[20];
  const float* noise1  = (const float*)d_in[21];
  const float* noise2  = (const float*)d_in[22];

  float* part1 = (float*)d_ws;
  float* part2 = part1 + (size_t)NMAT*NK*NBLOCKS;

  sde_kernel<<<NBLOCKS, TPB, 0, stream>>>(nW0, nb0, nW1, nb1, nW2, nb2, nW3, nb3,
                                          hW0, hb0, hW1, hb1, hW2, hb2, hW3, hb3,
                                          hW4, hb4, rho, V0, strikes, noise1, noise2,
                                          part1, part2);

  finalize_kernel<<<NMAT*NK, 256, 0, stream>>>(part1, part2, (float*)d_out);
}

// Round 7
// 309.585 us; speedup vs baseline: 70.4958x; 2.9601x over previous
//
#include <hip/hip_runtime.h>
#include <math.h>

#define TPB      128
#define NBLOCKS  512
#define PPB      16      // paths per block (16 MFMA cols)
#define BATCHN   8192
#define NMAT     4
#define PERS     24
#define NK       201
#define DSTR     124     // drift bounce row stride (halves)
#define HSTR     76      // hedge bounce row stride (halves)
#define GSTR     68      // Gsave row stride (floats)
#define GSC      (1.0f/4096.0f)   // exact pow2 pre-scale for f16 G fragments
#define GUNSC    4096.0f

typedef _Float16 f16;
typedef _Float16 f16x4 __attribute__((ext_vector_type(4)));
typedef _Float16 f16x8 __attribute__((ext_vector_type(8)));
typedef float    f32x4 __attribute__((ext_vector_type(4)));

template<int N> struct IC { static constexpr int v = N; };

// per-wave LDS write->read fence (bounce buffers are wave-private)
#define LDS_FENCE() asm volatile("s_waitcnt lgkmcnt(0)" ::: "memory")

__device__ __forceinline__ f16x8 relu8(f16x8 v){
#pragma unroll
  for (int i = 0; i < 8; ++i) v[i] = (v[i] > (f16)0.f) ? v[i] : (f16)0.f;
  return v;
}
__device__ __forceinline__ f16x8 cvt88(float4 a, float4 b){
  f16x8 r;
  r[0]=(f16)a.x; r[1]=(f16)a.y; r[2]=(f16)a.z; r[3]=(f16)a.w;
  r[4]=(f16)b.x; r[5]=(f16)b.y; r[6]=(f16)b.z; r[7]=(f16)b.w;
  return r;
}
__device__ __forceinline__ f16x4 cvt4(float4 a){
  f16x4 r; r[0]=(f16)a.x; r[1]=(f16)a.y; r[2]=(f16)a.z; r[3]=(f16)a.w; return r;
}

__global__ __launch_bounds__(TPB, 1)
void sde_kernel(const float* __restrict__ nW0, const float* __restrict__ nb0,
                const float* __restrict__ nW1, const float* __restrict__ nb1,
                const float* __restrict__ nW2, const float* __restrict__ nb2,
                const float* __restrict__ nW3, const float* __restrict__ nb3,
                const float* __restrict__ hW0, const float* __restrict__ hb0,
                const float* __restrict__ hW1, const float* __restrict__ hb1,
                const float* __restrict__ hW2, const float* __restrict__ hb2,
                const float* __restrict__ hW3, const float* __restrict__ hb3,
                const float* __restrict__ hW4, const float* __restrict__ hb4,
                const float* __restrict__ rho, const float* __restrict__ V0,
                const float* __restrict__ strikes,
                const float* __restrict__ noise1, const float* __restrict__ noise2,
                float* __restrict__ part1, float* __restrict__ part2)
{
  __shared__ __align__(16) f16   bbD [PPB*DSTR];     // drift bounce (wave 0 only)
  __shared__ __align__(16) f16   bbH1[PPB*HSTR];     // hedge bounces (wave 1 only)
  __shared__ __align__(16) f16   bbH2[PPB*HSTR];
  __shared__ __align__(16) float Gsave[NMAT*PPB*GSTR];
  __shared__ float mbS[2][PPB], mbc[2][PPB];         // mailbox drift -> hedge
  __shared__ float CstL[NMAT*PPB];
  __shared__ float SfinL[PPB];
  __shared__ float strikesL[NK];

  const int tid  = threadIdx.x;
  const int wv   = tid >> 6;          // 0 = drift wave, 1 = hedge wave
  const int lane = tid & 63;
  const int L15  = lane & 15;         // path (B/C col) OR weight/strike row (A row)
  const int G    = lane >> 4;         // lane quadrant
  const int gpath = blockIdx.x * PPB + L15;

  const float DTf = (float)(2.0/96.0);
  const float SDT = 0.14433756729740643f;           // sqrt(DT)
  const float DFf = (float)exp(-0.05 * 2.0 / 96.0);
  const float rho_s = rho[0];
  const float rt1m  = sqrtf(1.f - rho_s*rho_s);

  for (int k = tid; k < NK; k += TPB) strikesL[k] = strikes[k];

  float S = 100.f, Vv = V0[0];        // drift-wave state (per path, replicated over G)
  __syncthreads();

  auto maturity = [&](auto MC){
    constexpr int m = decltype(MC)::v;

    // ---------------- per-wave register staging ----------------
    f16x8 aD1[6], aD2[6];  f16x4 bD1r[6], bD2r[6];  f32x4 w3r[6];
    f16x8 w0r[3][4];       float b30=0.f, b31=0.f, b32=0.f;
    f16x8 aH[3][4][2];     f16x4 bHr[3][4];         f16x8 wh0r[2][3];
    float Gacc[16];        float Cacc = 0.f;
    float pn1 = 0.f, pn2 = 0.f;

    if (wv == 0){
#pragma unroll
      for (int t6 = 0; t6 < 6; ++t6){
        const int n  = t6 >> 1;
        const int o  = ((t6 & 1) << 4) + L15;
        const int ob = ((t6 & 1) << 4) + 4*G;
        const float* p1 = nW1 + (size_t)(((n*4+m)*32)+o)*32 + G*8;
        aD1[t6] = cvt88(*(const float4*)p1, *(const float4*)(p1+4));
        const float* p2 = nW2 + (size_t)(((n*4+m)*32)+o)*32 + G*8;
        aD2[t6] = cvt88(*(const float4*)p2, *(const float4*)(p2+4));
        bD1r[t6] = cvt4(*(const float4*)(nb1 + (n*4+m)*32 + ob));
        bD2r[t6] = cvt4(*(const float4*)(nb2 + (n*4+m)*32 + ob));
        w3r[t6]  = *(const f32x4*)(nW3 + (n*4+m)*32 + ob);
      }
      b30 = nb3[m]; b31 = nb3[4+m]; b32 = nb3[8+m];
#pragma unroll
      for (int n = 0; n < 3; ++n){
        f16x8 wt, ws, wvv, bz;
#pragma unroll
        for (int j = 0; j < 8; ++j){
          const int o = G*8 + j;
          const float* p = nW0 + (size_t)(((n*4+m)*32)+o)*3;
          wt[j]=(f16)p[0]; ws[j]=(f16)p[1]; wvv[j]=(f16)p[2];
          bz[j]=(f16)nb0[(n*4+m)*32+o];
        }
        w0r[n][0]=wt; w0r[n][1]=ws; w0r[n][2]=wvv; w0r[n][3]=bz;
      }
      pn1 = noise1[(size_t)(m*PERS)*BATCHN + gpath];
      pn2 = noise2[(size_t)(m*PERS)*BATCHN + gpath];
    } else {
#pragma unroll
      for (int L = 0; L < 3; ++L){
        const float* W = (L==0)?hW1:(L==1)?hW2:hW3;
        const float* B = (L==0)?hb1:(L==1)?hb2:hb3;
#pragma unroll
        for (int mt = 0; mt < 4; ++mt){
#pragma unroll
          for (int kt = 0; kt < 2; ++kt){
            const float* src = W + (size_t)m*4096 + (16*mt + L15)*64 + kt*32 + G*8;
            aH[L][mt][kt] = cvt88(*(const float4*)src, *(const float4*)(src+4));
          }
          bHr[L][mt] = cvt4(*(const float4*)(B + m*64 + mt*16 + 4*G));
        }
      }
#pragma unroll
      for (int kt = 0; kt < 2; ++kt){
        f16x8 wt, ws, bz;
#pragma unroll
        for (int j = 0; j < 8; ++j){
          const int o = kt*32 + G*8 + j;
          wt[j]=(f16)hW0[m*128 + o*2];
          ws[j]=(f16)hW0[m*128 + o*2 + 1];
          bz[j]=(f16)hb0[m*64 + o];
        }
        wh0r[kt][0]=wt; wh0r[kt][1]=ws; wh0r[kt][2]=bz;
      }
#pragma unroll
      for (int j = 0; j < 16; ++j) Gacc[j] = 0.f;
    }

    // ---------------- pipelined scan: drift step i || hedge step i-1 ----------------
#pragma unroll 1
    for (int i = 0; i <= PERS; ++i){
      if (wv == 0){
        if (i < PERS){
          const int gstep = m*PERS + i;
          const float t = (float)gstep * DTf;
          if (lane < PPB) mbS[i & 1][L15] = S;
          float nn1 = 0.f, nn2 = 0.f;
          if (i+1 < PERS){
            nn1 = noise1[(size_t)(gstep+1)*BATCHN + gpath];
            nn2 = noise2[(size_t)(gstep+1)*BATCHN + gpath];
          }
          const f16 th=(f16)t, Sh=(f16)S, Vh=(f16)Vv;
          f16x8 bfr[3];
#pragma unroll
          for (int n = 0; n < 3; ++n)
            bfr[n] = relu8(w0r[n][0]*th + w0r[n][1]*Sh + w0r[n][2]*Vh + w0r[n][3]);
#pragma unroll
          for (int t6 = 0; t6 < 6; ++t6){
            f32x4 acc = {(float)bD1r[t6][0],(float)bD1r[t6][1],(float)bD1r[t6][2],(float)bD1r[t6][3]};
            acc = __builtin_amdgcn_mfma_f32_16x16x32_f16(aD1[t6], bfr[t6>>1], acc, 0,0,0);
            f16x4 o4;
            o4[0]=(f16)fmaxf(acc[0],0.f); o4[1]=(f16)fmaxf(acc[1],0.f);
            o4[2]=(f16)fmaxf(acc[2],0.f); o4[3]=(f16)fmaxf(acc[3],0.f);
            *(f16x4*)&bbD[L15*DSTR + t6*16 + 4*G] = o4;
          }
          LDS_FENCE();
          f16x8 bl[3];
#pragma unroll
          for (int n = 0; n < 3; ++n)
            bl[n] = *(const f16x8*)&bbD[L15*DSTR + n*32 + G*8];
          f32x4 c2[6];
#pragma unroll
          for (int t6 = 0; t6 < 6; ++t6){
            f32x4 acc = {(float)bD2r[t6][0],(float)bD2r[t6][1],(float)bD2r[t6][2],(float)bD2r[t6][3]};
            c2[t6] = __builtin_amdgcn_mfma_f32_16x16x32_f16(aD2[t6], bl[t6>>1], acc, 0,0,0);
          }
          float pr0=0.f, pr1=0.f, pr2=0.f;
#pragma unroll
          for (int t6 = 0; t6 < 6; ++t6){
            const f32x4 w4 = w3r[t6];
            const float pp = w4[0]*fmaxf(c2[t6][0],0.f)+w4[1]*fmaxf(c2[t6][1],0.f)
                           + w4[2]*fmaxf(c2[t6][2],0.f)+w4[3]*fmaxf(c2[t6][3],0.f);
            if (t6<2) pr0+=pp; else if (t6<4) pr1+=pp; else pr2+=pp;
          }
          pr0 += __shfl_xor(pr0,16); pr0 += __shfl_xor(pr0,32);
          pr1 += __shfl_xor(pr1,16); pr1 += __shfl_xor(pr1,32);
          pr2 += __shfl_xor(pr2,16); pr2 += __shfl_xor(pr2,32);
          const float r0=pr0+b30, r1=pr1+b31, r2=pr2+b32;
          const float sigS = r0/(1.f+fabsf(r0)*SDT);
          const float bV   = r1/(1.f+fabsf(r1)*SDT);
          const float sigV = r2/(1.f+fabsf(r2)*SDT);
          const float sr = S*0.05f;
          const float bS = sr/(1.f+fabsf(sr)*SDT);
          const float dW = SDT*pn2;
          const float dB = rho_s*dW + rt1m*SDT*pn1;
          const float c  = DFf*S*sigS*dW;
          Cacc += c;
          if (lane < PPB) mbc[i & 1][L15] = c;
          S  = S + bS*DTf + sigS*dB;
          Vv = fmaxf(Vv + bV*DTf + sigV*dW, 0.f);
          pn1 = nn1; pn2 = nn2;
        }
      } else {
        if (i >= 1){
          const int s = i - 1;
          const float t = (float)(m*PERS + s) * DTf;
          const float Sj = mbS[s & 1][L15];
          const float c  = mbc[s & 1][L15];
          const f16 th=(f16)t, Sh=(f16)Sj;
          f16x8 bh0 = relu8(wh0r[0][0]*th + wh0r[0][1]*Sh + wh0r[0][2]);
          f16x8 bh1 = relu8(wh0r[1][0]*th + wh0r[1][1]*Sh + wh0r[1][2]);
#pragma unroll
          for (int mt = 0; mt < 4; ++mt){
            f32x4 acc = {(float)bHr[0][mt][0],(float)bHr[0][mt][1],(float)bHr[0][mt][2],(float)bHr[0][mt][3]};
            acc = __builtin_amdgcn_mfma_f32_16x16x32_f16(aH[0][mt][0], bh0, acc, 0,0,0);
            acc = __builtin_amdgcn_mfma_f32_16x16x32_f16(aH[0][mt][1], bh1, acc, 0,0,0);
            f16x4 o4;
            o4[0]=(f16)fmaxf(acc[0],0.f); o4[1]=(f16)fmaxf(acc[1],0.f);
            o4[2]=(f16)fmaxf(acc[2],0.f); o4[3]=(f16)fmaxf(acc[3],0.f);
            *(f16x4*)&bbH1[L15*HSTR + mt*16 + 4*G] = o4;
          }
          LDS_FENCE();
          f16x8 x0 = *(const f16x8*)&bbH1[L15*HSTR +      G*8];
          f16x8 x1 = *(const f16x8*)&bbH1[L15*HSTR + 32 + G*8];
#pragma unroll
          for (int mt = 0; mt < 4; ++mt){
            f32x4 acc = {(float)bHr[1][mt][0],(float)bHr[1][mt][1],(float)bHr[1][mt][2],(float)bHr[1][mt][3]};
            acc = __builtin_amdgcn_mfma_f32_16x16x32_f16(aH[1][mt][0], x0, acc, 0,0,0);
            acc = __builtin_amdgcn_mfma_f32_16x16x32_f16(aH[1][mt][1], x1, acc, 0,0,0);
            f16x4 o4;
            o4[0]=(f16)fmaxf(acc[0],0.f); o4[1]=(f16)fmaxf(acc[1],0.f);
            o4[2]=(f16)fmaxf(acc[2],0.f); o4[3]=(f16)fmaxf(acc[3],0.f);
            *(f16x4*)&bbH2[L15*HSTR + mt*16 + 4*G] = o4;
          }
          LDS_FENCE();
          x0 = *(const f16x8*)&bbH2[L15*HSTR +      G*8];
          x1 = *(const f16x8*)&bbH2[L15*HSTR + 32 + G*8];
#pragma unroll
          for (int mt = 0; mt < 4; ++mt){
            f32x4 acc = {(float)bHr[2][mt][0],(float)bHr[2][mt][1],(float)bHr[2][mt][2],(float)bHr[2][mt][3]};
            acc = __builtin_amdgcn_mfma_f32_16x16x32_f16(aH[2][mt][0], x0, acc, 0,0,0);
            acc = __builtin_amdgcn_mfma_f32_16x16x32_f16(aH[2][mt][1], x1, acc, 0,0,0);
            Gacc[mt*4+0] += c*fmaxf(acc[0],0.f);
            Gacc[mt*4+1] += c*fmaxf(acc[1],0.f);
            Gacc[mt*4+2] += c*fmaxf(acc[2],0.f);
            Gacc[mt*4+3] += c*fmaxf(acc[3],0.f);
          }
        }
      }
      __syncthreads();
    }

    // ---------------- post per-maturity results ----------------
    if (wv == 0){
      if (lane < PPB){ SfinL[L15] = S; CstL[m*PPB + L15] = Cacc; }
    } else {
#pragma unroll
      for (int mt = 0; mt < 4; ++mt){
        f32x4 gv = {Gacc[mt*4+0], Gacc[mt*4+1], Gacc[mt*4+2], Gacc[mt*4+3]};
        *(f32x4*)&Gsave[(size_t)(m*PPB + L15)*GSTR + mt*16 + 4*G] = gv;
      }
    }
    __syncthreads();

    // ---------------- epilogue (both waves, strike tiles split) ----------------
    {
      const float discm = (float)exp(-0.05*(2.0/96.0)*(double)(PERS*(m+1)));
      const float Sfin = SfinL[L15];
      float Cc[m+1];
      f16x8 Bf[m+1][2];
#pragma unroll
      for (int q = 0; q <= m; ++q){
        Cc[q] = CstL[q*PPB + L15];
#pragma unroll
        for (int kt = 0; kt < 2; ++kt){
          const float* gp = &Gsave[(size_t)(q*PPB + L15)*GSTR + kt*32 + G*8];
          const f32x4 g0 = *(const f32x4*)gp;
          const f32x4 g1 = *(const f32x4*)(gp + 4);
          f16x8 b;   // pre-scaled by 2^-12 (exact) to avoid f16 overflow of G
          b[0]=(f16)(g0[0]*GSC); b[1]=(f16)(g0[1]*GSC); b[2]=(f16)(g0[2]*GSC); b[3]=(f16)(g0[3]*GSC);
          b[4]=(f16)(g1[0]*GSC); b[5]=(f16)(g1[1]*GSC); b[6]=(f16)(g1[2]*GSC); b[7]=(f16)(g1[3]*GSC);
          Bf[q][kt] = b;
        }
      }
      for (int mt = wv; mt < 13; mt += 2){
        const int ksr = min(16*mt + L15, 200);
        f32x4 acc = {0.f, 0.f, 0.f, 0.f};
#pragma unroll
        for (int q = 0; q <= m; ++q){
#pragma unroll
          for (int kt = 0; kt < 2; ++kt){
            const float* ap = hW4 + (size_t)(q*804 + ksr*4 + m)*64 + kt*32 + G*8;
            const f16x8 a = cvt88(*(const float4*)ap, *(const float4*)(ap+4));
            acc = __builtin_amdgcn_mfma_f32_16x16x32_f16(a, Bf[q][kt], acc, 0,0,0);
          }
        }
#pragma unroll
        for (int r = 0; r < 4; ++r){
          const int k2  = 16*mt + 4*G + r;
          const int k2c = min(k2, 200);
          float ac = acc[r] * GUNSC;   // undo the 2^-12 G pre-scale
#pragma unroll
          for (int q = 0; q <= m; ++q)
            ac = fmaf(hb4[q*804 + k2c*4 + m], Cc[q], ac);
          const float pay = discm*fmaxf(Sfin - strikesL[k2c], 0.f) - ac;
          float s1 = pay, s2 = pay*pay;
          s1 += __shfl_xor(s1,1); s1 += __shfl_xor(s1,2);
          s1 += __shfl_xor(s1,4); s1 += __shfl_xor(s1,8);
          s2 += __shfl_xor(s2,1); s2 += __shfl_xor(s2,2);
          s2 += __shfl_xor(s2,4); s2 += __shfl_xor(s2,8);
          if (L15 == 0 && k2 < NK){
            part1[(size_t)(m*NK + k2)*NBLOCKS + blockIdx.x] = s1;
            part2[(size_t)(m*NK + k2)*NBLOCKS + blockIdx.x] = s2;
          }
        }
      }
    }
  };

  maturity(IC<0>{});
  maturity(IC<1>{});
  maturity(IC<2>{});
  maturity(IC<3>{});
}

__global__ __launch_bounds__(256)
void finalize_kernel(const float* __restrict__ part1,
                     const float* __restrict__ part2,
                     float* __restrict__ out)
{
  const int j   = blockIdx.x;          // j = m*NK + k
  const int m   = j / NK, k = j % NK;
  const int tid = threadIdx.x;
  double s1 = (double)part1[(size_t)j*NBLOCKS + tid]
            + (double)part1[(size_t)j*NBLOCKS + 256 + tid];
  double s2 = (double)part2[(size_t)j*NBLOCKS + tid]
            + (double)part2[(size_t)j*NBLOCKS + 256 + tid];
#pragma unroll
  for (int d = 32; d > 0; d >>= 1){
    s1 += __shfl_down(s1, d, 64);
    s2 += __shfl_down(s2, d, 64);
  }
  __shared__ double r1[4], r2[4];
  if ((tid & 63) == 0){ r1[tid>>6] = s1; r2[tid>>6] = s2; }
  __syncthreads();
  if (tid == 0){
    const double t1 = r1[0]+r1[1]+r1[2]+r1[3];
    const double t2 = r2[0]+r2[1]+r2[2]+r2[3];
    const double mean = t1 / 8192.0;
    const double var  = (t2 - t1*t1/8192.0) / 8191.0;   // ddof=1
    out[k*NMAT + m]            = (float)mean;
    out[NK*NMAT + k*NMAT + m]  = (float)var;
  }
}

extern "C" void kernel_launch(void* const* d_in, const int* in_sizes, int n_in,
                              void* d_out, int out_size, void* d_ws, size_t ws_size,
                              hipStream_t stream)
{
  (void)in_sizes; (void)n_in; (void)out_size; (void)ws_size;
  const float* nW0 = (const float*)d_in[0];
  const float* nb0 = (const float*)d_in[1];
  const float* nW1 = (const float*)d_in[2];
  const float* nb1 = (const float*)d_in[3];
  const float* nW2 = (const float*)d_in[4];
  const float* nb2 = (const float*)d_in[5];
  const float* nW3 = (const float*)d_in[6];
  const float* nb3 = (const float*)d_in[7];
  const float* hW0 = (const float*)d_in[8];
  const float* hb0 = (const float*)d_in[9];
  const float* hW1 = (const float*)d_in[10];
  const float* hb1 = (const float*)d_in[11];
  const float* hW2 = (const float*)d_in[12];
  const float* hb2 = (const float*)d_in[13];
  const float* hW3 = (const float*)d_in[14];
  const float* hb3 = (const float*)d_in[15];
  const float* hW4 = (const float*)d_in[16];
  const float* hb4 = (const float*)d_in[17];
  const float* rho = (const float*)d_in[18];
  const float* V0  = (const float*)d_in[19];
  const float* strikes = (const float*)d_in[20];
  const float* noise1  = (const float*)d_in[21];
  const float* noise2  = (const float*)d_in[22];

  float* part1 = (float*)d_ws;
  float* part2 = part1 + (size_t)NMAT*NK*NBLOCKS;

  sde_kernel<<<NBLOCKS, TPB, 0, stream>>>(nW0, nb0, nW1, nb1, nW2, nb2, nW3, nb3,
                                          hW0, hb0, hW1, hb1, hW2, hb2, hW3, hb3,
                                          hW4, hb4, rho, V0, strikes, noise1, noise2,
                                          part1, part2);

  finalize_kernel<<<NMAT*NK, 256, 0, stream>>>(part1, part2, (float*)d_out);
}